// Round 1
// baseline (1150.000 us; speedup 1.0000x reference)
//
#include <hip/hip_runtime.h>

#define NNODE 20000
#define NEDGE 500000

// ---------------------------------------------------------------------------
// GEMM: C[M,BN] = A[M,K] @ B[K,BN] + bias[BN], optional relu. fp32.
// BM=64, BK=64 tiles, 256 threads; each thread computes TM x 4 outputs.
// ---------------------------------------------------------------------------
template<int BN, int TM>
__global__ __launch_bounds__(256) void gemm_bias_kernel(
    const float* __restrict__ A, const float* __restrict__ B,
    const float* __restrict__ bias, float* __restrict__ C,
    int M, int K, int do_relu)
{
    constexpr int BM = 64, BK = 64;
    __shared__ float As[BK][BM + 4];   // +4 pad keeps rows 16B-aligned (68*4=272=16*17)
    __shared__ float Bs[BK][BN];
    const int tid = threadIdx.x;
    const int m0 = blockIdx.x * BM;
    constexpr int CG = BN / 4;                 // column groups (TN=4)
    const int rowBase = (tid / CG) * TM;
    const int colBase = (tid % CG) * 4;

    float acc[TM][4];
#pragma unroll
    for (int i = 0; i < TM; ++i)
#pragma unroll
        for (int j = 0; j < 4; ++j) acc[i][j] = 0.f;

    const bool k4 = ((K & 3) == 0);
    for (int k0 = 0; k0 < K; k0 += BK) {
        // ---- A tile (transposed into LDS) ----
        if (k4) {
#pragma unroll
            for (int it = 0; it < 4; ++it) {
                int idx = tid + it * 256;       // float4 slot 0..1023
                int row = idx >> 4;
                int c4  = idx & 15;
                int k = k0 + c4 * 4;
                int gr = m0 + row;
                float4 v = make_float4(0.f, 0.f, 0.f, 0.f);
                if (gr < M && k < K)
                    v = *reinterpret_cast<const float4*>(A + (size_t)gr * K + k);
                As[c4 * 4 + 0][row] = v.x;
                As[c4 * 4 + 1][row] = v.y;
                As[c4 * 4 + 2][row] = v.z;
                As[c4 * 4 + 3][row] = v.w;
            }
        } else {                                // K % 4 != 0 (K=300): scalar loads
#pragma unroll
            for (int it = 0; it < 16; ++it) {
                int idx = tid + it * 256;       // 0..4095
                int row = idx >> 6;
                int kk  = idx & 63;
                int gr = m0 + row;
                int k = k0 + kk;
                float v = 0.f;
                if (gr < M && k < K) v = A[(size_t)gr * K + k];
                As[kk][row] = v;
            }
        }
        // ---- B tile ----
        constexpr int NF4 = BK * BN / 4;
#pragma unroll
        for (int it = 0; it < NF4 / 256; ++it) {
            int idx = tid + it * 256;
            int row = idx / (BN / 4);
            int c4  = idx % (BN / 4);
            int k = k0 + row;
            float4 v = make_float4(0.f, 0.f, 0.f, 0.f);
            if (k < K)
                v = *reinterpret_cast<const float4*>(B + (size_t)k * BN + c4 * 4);
            *reinterpret_cast<float4*>(&Bs[row][c4 * 4]) = v;
        }
        __syncthreads();
#pragma unroll 4
        for (int kk = 0; kk < BK; ++kk) {
            float4 b = *reinterpret_cast<const float4*>(&Bs[kk][colBase]);
#pragma unroll
            for (int i = 0; i < TM; i += 4) {
                float4 a = *reinterpret_cast<const float4*>(&As[kk][rowBase + i]);
                acc[i+0][0] += a.x * b.x; acc[i+0][1] += a.x * b.y; acc[i+0][2] += a.x * b.z; acc[i+0][3] += a.x * b.w;
                acc[i+1][0] += a.y * b.x; acc[i+1][1] += a.y * b.y; acc[i+1][2] += a.y * b.z; acc[i+1][3] += a.y * b.w;
                acc[i+2][0] += a.z * b.x; acc[i+2][1] += a.z * b.y; acc[i+2][2] += a.z * b.z; acc[i+2][3] += a.z * b.w;
                acc[i+3][0] += a.w * b.x; acc[i+3][1] += a.w * b.y; acc[i+3][2] += a.w * b.z; acc[i+3][3] += a.w * b.w;
            }
        }
        __syncthreads();
    }
    float4 bv = *reinterpret_cast<const float4*>(bias + colBase);
#pragma unroll
    for (int i = 0; i < TM; ++i) {
        int gr = m0 + rowBase + i;
        if (gr < M) {
            float4 o;
            o.x = acc[i][0] + bv.x;
            o.y = acc[i][1] + bv.y;
            o.z = acc[i][2] + bv.z;
            o.w = acc[i][3] + bv.w;
            if (do_relu) {
                o.x = fmaxf(o.x, 0.f); o.y = fmaxf(o.y, 0.f);
                o.z = fmaxf(o.z, 0.f); o.w = fmaxf(o.w, 0.f);
            }
            *reinterpret_cast<float4*>(C + (size_t)gr * BN + colBase) = o;
        }
    }
}

// ---------------------------------------------------------------------------
// CSR build: count -> scan (3 relations in one launch) -> fill
// ---------------------------------------------------------------------------
__global__ __launch_bounds__(256) void count_kernel(
    const int* __restrict__ dst, int* __restrict__ cnt, int n)
{
    int i = blockIdx.x * 256 + threadIdx.x;
    if (i < n) atomicAdd(&cnt[dst[i]], 1);
}

__global__ __launch_bounds__(1024) void scan3_kernel(
    const int* __restrict__ c0, int* __restrict__ o0,
    const int* __restrict__ c1, int* __restrict__ o1,
    const int* __restrict__ c2, int* __restrict__ o2, int n)
{
    const int* cnt = (blockIdx.x == 0) ? c0 : (blockIdx.x == 1) ? c1 : c2;
    int* off       = (blockIdx.x == 0) ? o0 : (blockIdx.x == 1) ? o1 : o2;
    __shared__ int sdata[1024];
    __shared__ int s_carry;
    int tid = threadIdx.x;
    if (tid == 0) s_carry = 0;
    __syncthreads();
    for (int base = 0; base < n; base += 1024) {
        int i = base + tid;
        int v = (i < n) ? cnt[i] : 0;
        sdata[tid] = v;
        __syncthreads();
        for (int s = 1; s < 1024; s <<= 1) {
            int t = (tid >= s) ? sdata[tid - s] : 0;
            __syncthreads();
            sdata[tid] += t;
            __syncthreads();
        }
        int carry = s_carry;
        if (i < n) off[i] = carry + sdata[tid] - v;   // exclusive
        __syncthreads();
        if (tid == 0) s_carry = carry + sdata[1023];
        __syncthreads();
    }
    if (tid == 0) off[n] = s_carry;
}

__global__ __launch_bounds__(256) void fill_kernel(
    const int* __restrict__ src, const int* __restrict__ dst,
    const int* __restrict__ off, int* __restrict__ cur,
    int* __restrict__ csrc, int n)
{
    int i = blockIdx.x * 256 + threadIdx.x;
    if (i < n) {
        int d = dst[i];
        int slot = off[d] + atomicAdd(&cur[d], 1);
        csrc[slot] = src[i];
    }
}

// ---------------------------------------------------------------------------
// acc init: acc[i,:] = scale * (b1 + b2)
// ---------------------------------------------------------------------------
__global__ __launch_bounds__(256) void init_acc_kernel(
    float* __restrict__ acc, const float* __restrict__ b1,
    const float* __restrict__ b2, float scale, int nrows)
{
    int i = blockIdx.x * 256 + threadIdx.x;
    if (i < nrows * 128) {
        int j = i & 127;
        float v = b1[j];
        if (b2) v += b2[j];
        acc[i] = v * scale;
    }
}

// ---------------------------------------------------------------------------
// Fused GATv2 conv, CSR (per-dst) form. 32 lanes = one dst row.
// lane l owns elements 4l..4l+3 of the 128-vector [H=4,O=32]; head h = l/8.
// Pass 1: online softmax stats (max + rescaled sum) per head, in registers.
// Pass 2: recompute score, accumulate alpha * fs[src]. acc is RMW (no atomics).
// ---------------------------------------------------------------------------
__global__ __launch_bounds__(256) void gat_conv_kernel(
    const float* __restrict__ fs, const float* __restrict__ fd,
    const int* __restrict__ off, const int* __restrict__ csrc,
    const float* __restrict__ attn,
    float* __restrict__ acc, float scale, int n_dst)
{
    int gid = blockIdx.x * 256 + threadIdx.x;
    int d = gid >> 5;
    int lane = gid & 31;
    if (d >= n_dst) return;
    const int e0 = off[d], e1 = off[d + 1];
    const float4* fs4 = reinterpret_cast<const float4*>(fs);
    const float4 fdv = reinterpret_cast<const float4*>(fd)[(size_t)d * 32 + lane];
    const float4 av  = reinterpret_cast<const float4*>(attn)[lane];

    float mx = -3.0e38f;
    float ssum = 0.f;
    for (int i = e0; i < e1; ++i) {
        int s_ = csrc[i];
        float4 u = fs4[(size_t)s_ * 32 + lane];
        float4 v;
        v.x = u.x + fdv.x; v.y = u.y + fdv.y; v.z = u.z + fdv.z; v.w = u.w + fdv.w;
        v.x = v.x > 0.f ? v.x : 0.2f * v.x;
        v.y = v.y > 0.f ? v.y : 0.2f * v.y;
        v.z = v.z > 0.f ? v.z : 0.2f * v.z;
        v.w = v.w > 0.f ? v.w : 0.2f * v.w;
        float p = v.x * av.x + v.y * av.y + v.z * av.z + v.w * av.w;
        p += __shfl_xor(p, 1);
        p += __shfl_xor(p, 2);
        p += __shfl_xor(p, 4);          // all 8 lanes of the head hold score
        float mo = mx;
        mx = fmaxf(mx, p);
        ssum = ssum * __expf(mo - mx) + __expf(p - mx);
    }
    float rs = (ssum > 0.f) ? 1.f / ssum : 0.f;

    float4 a4 = make_float4(0.f, 0.f, 0.f, 0.f);
    for (int i = e0; i < e1; ++i) {
        int s_ = csrc[i];
        float4 u = fs4[(size_t)s_ * 32 + lane];
        float4 v;
        v.x = u.x + fdv.x; v.y = u.y + fdv.y; v.z = u.z + fdv.z; v.w = u.w + fdv.w;
        v.x = v.x > 0.f ? v.x : 0.2f * v.x;
        v.y = v.y > 0.f ? v.y : 0.2f * v.y;
        v.z = v.z > 0.f ? v.z : 0.2f * v.z;
        v.w = v.w > 0.f ? v.w : 0.2f * v.w;
        float p = v.x * av.x + v.y * av.y + v.z * av.z + v.w * av.w;
        p += __shfl_xor(p, 1);
        p += __shfl_xor(p, 2);
        p += __shfl_xor(p, 4);
        float alpha = __expf(p - mx) * rs;
        a4.x += alpha * u.x; a4.y += alpha * u.y;
        a4.z += alpha * u.z; a4.w += alpha * u.w;
    }
    float* op = acc + (size_t)d * 128 + lane * 4;
    float4 cur = *reinterpret_cast<float4*>(op);
    cur.x += scale * a4.x; cur.y += scale * a4.y;
    cur.z += scale * a4.z; cur.w += scale * a4.w;
    *reinterpret_cast<float4*>(op) = cur;
}

// ---------------------------------------------------------------------------
extern "C" void kernel_launch(void* const* d_in, const int* in_sizes, int n_in,
                              void* d_out, int out_size, void* d_ws, size_t ws_size,
                              hipStream_t stream)
{
    const float* x_word  = (const float*)d_in[0];
    const float* x_doc   = (const float*)d_in[1];
    const float* Wp_word = (const float*)d_in[2];
    const float* bp_word = (const float*)d_in[3];
    const float* Wp_doc  = (const float*)d_in[4];
    const float* bp_doc  = (const float*)d_in[5];
    const float* Wsrc    = (const float*)d_in[6];
    const float* bsrc    = (const float*)d_in[7];
    const float* Wdst    = (const float*)d_in[8];
    const float* bdst    = (const float*)d_in[9];
    const float* attn    = (const float*)d_in[10];
    const float* bconv   = (const float*)d_in[11];
    const float* Wc1     = (const float*)d_in[12];
    const float* bc1     = (const float*)d_in[13];
    const float* Wc2     = (const float*)d_in[14];
    const float* bc2     = (const float*)d_in[15];
    const int* src_wd = (const int*)d_in[16];
    const int* dst_wd = (const int*)d_in[17];
    const int* src_dw = (const int*)d_in[18];
    const int* dst_dw = (const int*)d_in[19];
    const int* src_dd = (const int*)d_in[20];
    const int* dst_dd = (const int*)d_in[21];

    // ---- workspace layout ----
    const size_t NN = (size_t)NNODE * 128;
    float* F   = (float*)d_ws;
    float* hw0 = F;              float* hd0 = F + NN;
    float* hw1 = F + 2 * NN;     float* hd1 = F + 3 * NN;
    float* fs  = F + 4 * NN;     float* fd  = F + 5 * NN;
    float* z   = F + 6 * NN;                       // 20000*64
    int* I    = (int*)(F + 6 * NN + (size_t)NNODE * 64);
    int* cnt  = I;                                 // 3*20000 (reused as fill cursors)
    int* off0 = I + 3 * NNODE;
    int* off1 = off0 + (NNODE + 4);
    int* off2 = off1 + (NNODE + 4);
    int* csr0 = off2 + (NNODE + 4);                // NEDGE each
    int* csr1 = csr0 + NEDGE;
    int* csr2 = csr1 + NEDGE;

    const int EB = (NEDGE + 255) / 256;
    const int GB = (NNODE + 63) / 64;              // 313 GEMM blocks
    const int CB = (NNODE * 32) / 256;             // 2500 conv blocks

    // ---- CSR build (once; reused by both layers) ----
    (void)hipMemsetAsync(cnt, 0, 3 * NNODE * sizeof(int), stream);
    count_kernel<<<EB, 256, 0, stream>>>(dst_wd, cnt,             NEDGE);
    count_kernel<<<EB, 256, 0, stream>>>(dst_dw, cnt + NNODE,     NEDGE);
    count_kernel<<<EB, 256, 0, stream>>>(dst_dd, cnt + 2 * NNODE, NEDGE);
    scan3_kernel<<<3, 1024, 0, stream>>>(cnt, off0, cnt + NNODE, off1, cnt + 2 * NNODE, off2, NNODE);
    (void)hipMemsetAsync(cnt, 0, 3 * NNODE * sizeof(int), stream);
    fill_kernel<<<EB, 256, 0, stream>>>(src_wd, dst_wd, off0, cnt,             csr0, NEDGE);
    fill_kernel<<<EB, 256, 0, stream>>>(src_dw, dst_dw, off1, cnt + NNODE,     csr1, NEDGE);
    fill_kernel<<<EB, 256, 0, stream>>>(src_dd, dst_dd, off2, cnt + 2 * NNODE, csr2, NEDGE);

    auto gemm128 = [&](const float* A, const float* B, const float* b, float* C, int K) {
        gemm_bias_kernel<128, 8><<<GB, 256, 0, stream>>>(A, B, b, C, NNODE, K, 0);
    };

    // ---- input projections ----
    float* hw = hw0; float* hd = hd0; float* hwn = hw1; float* hdn = hd1;
    gemm128(x_word, Wp_word, bp_word, hw, 300);
    gemm128(x_doc,  Wp_doc,  bp_doc,  hd, 128);

    // ---- 2 GAT layers ----
    for (int l = 0; l < 2; ++l) {
        init_acc_kernel<<<(NNODE * 128) / 256, 256, 0, stream>>>(
            hdn, bconv + (l * 3 + 0) * 128, bconv + (l * 3 + 2) * 128, 0.5f, NNODE);
        init_acc_kernel<<<(NNODE * 128) / 256, 256, 0, stream>>>(
            hwn, bconv + (l * 3 + 1) * 128, nullptr, 1.0f, NNODE);

        // relation r: fs = h_src @ Wsrc + bsrc ; fd = h_dst @ Wdst + bdst ; fused conv
        struct Rel { const float* hs; const float* hdp; const int* off; const int* csr;
                     float* accp; float scl; };
        const Rel rels[3] = {
            { hw, hd, off0, csr0, hdn, 0.5f },   // word -> doc
            { hd, hw, off1, csr1, hwn, 1.0f },   // doc  -> word
            { hd, hd, off2, csr2, hdn, 0.5f },   // doc  -> doc
        };
        for (int r = 0; r < 3; ++r) {
            int idx = l * 3 + r;
            gemm128(rels[r].hs,  Wsrc + (size_t)idx * 16384, bsrc + idx * 128, fs, 128);
            gemm128(rels[r].hdp, Wdst + (size_t)idx * 16384, bdst + idx * 128, fd, 128);
            gat_conv_kernel<<<CB, 256, 0, stream>>>(
                fs, fd, rels[r].off, rels[r].csr, attn + idx * 128,
                rels[r].accp, rels[r].scl, NNODE);
        }
        float* t;
        t = hw; hw = hwn; hwn = t;
        t = hd; hd = hdn; hdn = t;
    }

    // ---- final MLP: z = relu(h_d @ Wc1 + bc1); out = z @ Wc2 + bc2 ----
    gemm_bias_kernel<64, 4><<<GB, 256, 0, stream>>>(hd, Wc1, bc1, z, NNODE, 128, 1);
    gemm_bias_kernel<64, 4><<<GB, 256, 0, stream>>>(z, Wc2, bc2, (float*)d_out, NNODE, 64, 0);
}

// Round 2
// 798.538 us; speedup vs baseline: 1.4401x; 1.4401x over previous
//
#include <hip/hip_runtime.h>

#define NNODE 20000
#define NEDGE 500000

typedef __attribute__((ext_vector_type(8))) short bf16x8;
typedef __attribute__((ext_vector_type(8))) unsigned short u16x8;
typedef __attribute__((ext_vector_type(4))) float f32x4;

// ---------------------------------------------------------------------------
// bf16 split helpers (RNE)
// ---------------------------------------------------------------------------
__device__ __forceinline__ unsigned short f2bf(float f) {
    unsigned u = __float_as_uint(f);
    unsigned r = (u + 0x7FFFu + ((u >> 16) & 1u)) >> 16;
    return (unsigned short)r;
}
__device__ __forceinline__ float bf2f(unsigned short h) {
    return __uint_as_float((unsigned)h << 16);
}

// ---------------------------------------------------------------------------
// split_a: X[M][K] fp32 -> A2[M][2*Kp] bf16 (cols [0,Kp)=hi, [Kp,2Kp)=lo)
// ---------------------------------------------------------------------------
__global__ __launch_bounds__(256) void split_a_kernel(
    const float* __restrict__ X, unsigned short* __restrict__ A2,
    int M, int K, int Kp)
{
    int i = blockIdx.x * 256 + threadIdx.x;
    int per = Kp >> 2;
    if (i >= M * per) return;
    int r = i / per, c = (i % per) * 4;
    float v[4];
    if ((K & 3) == 0) {
        float4 t = *reinterpret_cast<const float4*>(X + (size_t)r * K + c);
        v[0] = t.x; v[1] = t.y; v[2] = t.z; v[3] = t.w;
    } else {
#pragma unroll
        for (int j = 0; j < 4; ++j) v[j] = (c + j < K) ? X[(size_t)r * K + c + j] : 0.f;
    }
    ushort4 hi, lo;
    unsigned short h;
    h = f2bf(v[0]); hi.x = h; lo.x = f2bf(v[0] - bf2f(h));
    h = f2bf(v[1]); hi.y = h; lo.y = f2bf(v[1] - bf2f(h));
    h = f2bf(v[2]); hi.z = h; lo.z = f2bf(v[2] - bf2f(h));
    h = f2bf(v[3]); hi.w = h; lo.w = f2bf(v[3] - bf2f(h));
    *reinterpret_cast<ushort4*>(A2 + (size_t)r * 2 * Kp + c) = hi;
    *reinterpret_cast<ushort4*>(A2 + (size_t)r * 2 * Kp + Kp + c) = lo;
}

// ---------------------------------------------------------------------------
// split_b (batched): B[mat][K][N] fp32 -> Bt[mat][2][N][Kp] bf16, transposed
// ---------------------------------------------------------------------------
__global__ __launch_bounds__(256) void split_b_kernel(
    const float* __restrict__ B0, unsigned short* __restrict__ Bt0,
    int K, int N, int Kp)
{
    int mat = blockIdx.y;
    const float* B = B0 + (size_t)mat * K * N;
    unsigned short* Bt = Bt0 + (size_t)mat * 2 * N * Kp;
    int i = blockIdx.x * 256 + threadIdx.x;
    if (i >= N * Kp) return;
    int n = i / Kp, k = i % Kp;
    float v = (k < K) ? B[(size_t)k * N + n] : 0.f;
    unsigned short h = f2bf(v);
    Bt[i] = h;
    Bt[(size_t)N * Kp + i] = f2bf(v - bf2f(h));
}

// ---------------------------------------------------------------------------
// Split-bf16 MFMA GEMM: C[M][BN] = A[M][Kp](fp32 as hi+lo) @ B + bias.
// 3 segments: Ahi*Bhi + Alo*Bhi + Ahi*Blo. BM=64, BK=32, 256 thr = 2x2 waves,
// wave tile 32 x BN/2 of 16x16x32 bf16 MFMA fragments.
// ---------------------------------------------------------------------------
template<int BN>
__global__ __launch_bounds__(256) void gemm_mfma_kernel(
    const unsigned short* __restrict__ A2,   // [M][2*Kp]
    const unsigned short* __restrict__ Bt,   // [2][BN][Kp]
    const float* __restrict__ bias,
    float* __restrict__ C, int M, int Kp, int do_relu)
{
    constexpr int BM = 64;
    constexpr int FN = BN / 32;              // B frags per wave
    __shared__ unsigned short As[BM][40];    // 32 bf16 + 8 pad (80B rows)
    __shared__ unsigned short Bs[BN][40];
    const int tid = threadIdx.x;
    const int m0 = blockIdx.x * BM;
    const int wid = tid >> 6, lane = tid & 63;
    const int wm = wid >> 1, wn = wid & 1;
    const int lr = lane & 15, kg = lane >> 4;

    f32x4 acc[2][FN] = {};
    const size_t KA = 2 * (size_t)Kp;

    for (int seg = 0; seg < 3; ++seg) {
        const unsigned short* Ab = A2 + (seg == 1 ? Kp : 0);
        const unsigned short* Bb = Bt + (seg == 2 ? (size_t)BN * Kp : 0);
        for (int k0 = 0; k0 < Kp; k0 += 32) {
            {   // stage A tile 64x32
                int row = tid >> 2, ck = tid & 3;
                u16x8 av = {0, 0, 0, 0, 0, 0, 0, 0};
                if (m0 + row < M)
                    av = *reinterpret_cast<const u16x8*>(
                        Ab + (size_t)(m0 + row) * KA + k0 + ck * 8);
                *reinterpret_cast<u16x8*>(&As[row][ck * 8]) = av;
            }
#pragma unroll
            for (int it = 0; it < BN / 64; ++it) {   // stage B tile BNx32
                int idx = tid + it * 256;
                int nr = idx >> 2, ck = idx & 3;
                u16x8 bv = *reinterpret_cast<const u16x8*>(
                    Bb + (size_t)nr * Kp + k0 + ck * 8);
                *reinterpret_cast<u16x8*>(&Bs[nr][ck * 8]) = bv;
            }
            __syncthreads();
            bf16x8 af[2], bfr[FN];
#pragma unroll
            for (int fm = 0; fm < 2; ++fm)
                af[fm] = *reinterpret_cast<const bf16x8*>(
                    &As[wm * 32 + fm * 16 + lr][kg * 8]);
#pragma unroll
            for (int fn = 0; fn < FN; ++fn)
                bfr[fn] = *reinterpret_cast<const bf16x8*>(
                    &Bs[wn * (BN / 2) + fn * 16 + lr][kg * 8]);
#pragma unroll
            for (int fm = 0; fm < 2; ++fm)
#pragma unroll
                for (int fn = 0; fn < FN; ++fn)
                    acc[fm][fn] = __builtin_amdgcn_mfma_f32_16x16x32_bf16(
                        af[fm], bfr[fn], acc[fm][fn], 0, 0, 0);
            __syncthreads();
        }
    }
    // epilogue: C/D map (m89-verified): col = lane&15, row = (lane>>4)*4 + j
#pragma unroll
    for (int fm = 0; fm < 2; ++fm)
#pragma unroll
        for (int fn = 0; fn < FN; ++fn) {
            int gc = wn * (BN / 2) + fn * 16 + lr;
            float bv = bias[gc];
#pragma unroll
            for (int j = 0; j < 4; ++j) {
                int gr = m0 + wm * 32 + fm * 16 + kg * 4 + j;
                if (gr < M) {
                    float v = acc[fm][fn][j] + bv;
                    if (do_relu) v = fmaxf(v, 0.f);
                    C[(size_t)gr * BN + gc] = v;
                }
            }
        }
}

// ---------------------------------------------------------------------------
// CSR build: count -> shfl-scan (3 relations) -> fill
// ---------------------------------------------------------------------------
__global__ __launch_bounds__(256) void count_kernel(
    const int* __restrict__ dst, int* __restrict__ cnt, int n)
{
    int i = blockIdx.x * 256 + threadIdx.x;
    if (i < n) atomicAdd(&cnt[dst[i]], 1);
}

__global__ __launch_bounds__(1024) void scan3_kernel(
    const int* __restrict__ c0, int* __restrict__ o0,
    const int* __restrict__ c1, int* __restrict__ o1,
    const int* __restrict__ c2, int* __restrict__ o2, int n)
{
    const int* cnt = (blockIdx.x == 0) ? c0 : (blockIdx.x == 1) ? c1 : c2;
    int* off       = (blockIdx.x == 0) ? o0 : (blockIdx.x == 1) ? o1 : o2;
    __shared__ int wsum[16];
    __shared__ int s_carry;
    const int tid = threadIdx.x, lane = tid & 63, wid = tid >> 6;
    if (tid == 0) s_carry = 0;
    __syncthreads();
    for (int base = 0; base < n; base += 1024) {
        int i = base + tid;
        int orig = (i < n) ? cnt[i] : 0;
        int v = orig;
#pragma unroll
        for (int s = 1; s < 64; s <<= 1) {
            int t = __shfl_up(v, s);
            if (lane >= s) v += t;
        }
        if (lane == 63) wsum[wid] = v;
        __syncthreads();
        if (wid == 0) {
            int wv = (lane < 16) ? wsum[lane] : 0;
#pragma unroll
            for (int s = 1; s < 16; s <<= 1) {
                int t = __shfl_up(wv, s);
                if (lane >= s) wv += t;
            }
            if (lane < 16) wsum[lane] = wv;
        }
        __syncthreads();
        int carry = s_carry;
        int pre = (wid > 0) ? wsum[wid - 1] : 0;
        if (i < n) off[i] = carry + pre + v - orig;   // exclusive
        __syncthreads();
        if (tid == 1023) s_carry = carry + wsum[15];
        __syncthreads();
    }
    if (tid == 0) off[n] = s_carry;
}

__global__ __launch_bounds__(256) void fill_kernel(
    const int* __restrict__ src, const int* __restrict__ dst,
    const int* __restrict__ off, int* __restrict__ cur,
    int* __restrict__ csrc, int n)
{
    int i = blockIdx.x * 256 + threadIdx.x;
    if (i < n) {
        int d = dst[i];
        int slot = off[d] + atomicAdd(&cur[d], 1);
        csrc[slot] = src[i];
    }
}

__global__ __launch_bounds__(256) void init_acc_kernel(
    float* __restrict__ acc, const float* __restrict__ b1,
    const float* __restrict__ b2, float scale, int nrows)
{
    int i = blockIdx.x * 256 + threadIdx.x;
    if (i < nrows * 128) {
        int j = i & 127;
        float v = b1[j];
        if (b2) v += b2[j];
        acc[i] = v * scale;
    }
}

// ---------------------------------------------------------------------------
// Fused GATv2 conv — SINGLE PASS (flash-style online softmax).
// 32 lanes = one dst row; lane l owns elems 4l..4l+3; head = l/8.
// ---------------------------------------------------------------------------
__global__ __launch_bounds__(256) void gat_conv_kernel(
    const float* __restrict__ fs, const float* __restrict__ fd,
    const int* __restrict__ off, const int* __restrict__ csrc,
    const float* __restrict__ attn,
    float* __restrict__ acc, float scale, int n_dst)
{
    int gid = blockIdx.x * 256 + threadIdx.x;
    int d = gid >> 5;
    int lane = gid & 31;
    if (d >= n_dst) return;
    const int e0 = off[d], e1 = off[d + 1];
    const float4* fs4 = reinterpret_cast<const float4*>(fs);
    const float4 fdv = reinterpret_cast<const float4*>(fd)[(size_t)d * 32 + lane];
    const float4 av  = reinterpret_cast<const float4*>(attn)[lane];

    float mx = -3.0e38f, ssum = 0.f;
    float4 a4 = make_float4(0.f, 0.f, 0.f, 0.f);
    for (int i = e0; i < e1; ++i) {
        int s_ = csrc[i];
        float4 u = fs4[(size_t)s_ * 32 + lane];
        float4 v;
        v.x = u.x + fdv.x; v.y = u.y + fdv.y; v.z = u.z + fdv.z; v.w = u.w + fdv.w;
        v.x = v.x > 0.f ? v.x : 0.2f * v.x;
        v.y = v.y > 0.f ? v.y : 0.2f * v.y;
        v.z = v.z > 0.f ? v.z : 0.2f * v.z;
        v.w = v.w > 0.f ? v.w : 0.2f * v.w;
        float p = v.x * av.x + v.y * av.y + v.z * av.z + v.w * av.w;
        p += __shfl_xor(p, 1);
        p += __shfl_xor(p, 2);
        p += __shfl_xor(p, 4);          // all 8 lanes of head hold the score
        float mnew = fmaxf(mx, p);
        float f = __expf(mx - mnew);    // 1 if no new max; 0 on first edge
        float w = __expf(p - mnew);
        ssum = ssum * f + w;
        a4.x = a4.x * f + w * u.x;
        a4.y = a4.y * f + w * u.y;
        a4.z = a4.z * f + w * u.z;
        a4.w = a4.w * f + w * u.w;
        mx = mnew;
    }
    float rs = (ssum > 0.f) ? scale / ssum : 0.f;
    float* op = acc + (size_t)d * 128 + lane * 4;
    float4 cur = *reinterpret_cast<float4*>(op);
    cur.x += rs * a4.x; cur.y += rs * a4.y;
    cur.z += rs * a4.z; cur.w += rs * a4.w;
    *reinterpret_cast<float4*>(op) = cur;
}

// ---------------------------------------------------------------------------
extern "C" void kernel_launch(void* const* d_in, const int* in_sizes, int n_in,
                              void* d_out, int out_size, void* d_ws, size_t ws_size,
                              hipStream_t stream)
{
    const float* x_word  = (const float*)d_in[0];
    const float* x_doc   = (const float*)d_in[1];
    const float* Wp_word = (const float*)d_in[2];
    const float* bp_word = (const float*)d_in[3];
    const float* Wp_doc  = (const float*)d_in[4];
    const float* bp_doc  = (const float*)d_in[5];
    const float* Wsrc    = (const float*)d_in[6];
    const float* bsrc    = (const float*)d_in[7];
    const float* Wdst    = (const float*)d_in[8];
    const float* bdst    = (const float*)d_in[9];
    const float* attn    = (const float*)d_in[10];
    const float* bconv   = (const float*)d_in[11];
    const float* Wc1     = (const float*)d_in[12];
    const float* bc1     = (const float*)d_in[13];
    const float* Wc2     = (const float*)d_in[14];
    const float* bc2     = (const float*)d_in[15];
    const int* src_wd = (const int*)d_in[16];
    const int* dst_wd = (const int*)d_in[17];
    const int* src_dw = (const int*)d_in[18];
    const int* dst_dw = (const int*)d_in[19];
    const int* src_dd = (const int*)d_in[20];
    const int* dst_dd = (const int*)d_in[21];

    // ---- workspace layout ----
    const size_t NF = (size_t)NNODE * 128;           // 2.56M floats
    float* F   = (float*)d_ws;
    float* hw0 = F;              float* hd0 = F + NF;
    float* hw1 = F + 2 * NF;     float* hd1 = F + 3 * NF;
    float* fs  = F + 4 * NF;     float* fd  = F + 5 * NF;
    float* z   = F + 6 * NF;                         // 20000*64
    unsigned short* U = (unsigned short*)(F + 6 * NF + (size_t)NNODE * 64);
    unsigned short* Ax    = U;                       // 20000*640 (x_word / z splits)
    unsigned short* Asw   = Ax  + (size_t)NNODE * 640;
    unsigned short* Asd   = Asw + (size_t)NNODE * 256;
    unsigned short* WtPw  = Asd + (size_t)NNODE * 256;   // 2*128*320
    unsigned short* WtPd  = WtPw + 81920;                // 2*128*128
    unsigned short* WtS   = WtPd + 32768;                // 6 * 2*128*128
    unsigned short* WtD   = WtS  + 196608;
    unsigned short* WtC1  = WtD  + 196608;               // 2*64*128
    unsigned short* WtC2  = WtC1 + 16384;                // 2*64*64
    int* I    = (int*)(WtC2 + 8192);
    int* cnt  = I;                                   // 3*20000
    int* off0 = I + 3 * NNODE;
    int* off1 = off0 + 20004;
    int* off2 = off1 + 20004;
    int* csr0 = off2 + 20004;
    int* csr1 = csr0 + NEDGE;
    int* csr2 = csr1 + NEDGE;

    const int EB = (NEDGE + 255) / 256;
    const int GB = (NNODE + 63) / 64;                // 313 GEMM blocks
    const int CB = (NNODE * 32) / 256;               // 2500 conv blocks

    // ---- CSR build (reused by both layers) ----
    (void)hipMemsetAsync(cnt, 0, 3 * NNODE * sizeof(int), stream);
    count_kernel<<<EB, 256, 0, stream>>>(dst_wd, cnt,             NEDGE);
    count_kernel<<<EB, 256, 0, stream>>>(dst_dw, cnt + NNODE,     NEDGE);
    count_kernel<<<EB, 256, 0, stream>>>(dst_dd, cnt + 2 * NNODE, NEDGE);
    scan3_kernel<<<3, 1024, 0, stream>>>(cnt, off0, cnt + NNODE, off1,
                                         cnt + 2 * NNODE, off2, NNODE);
    (void)hipMemsetAsync(cnt, 0, 3 * NNODE * sizeof(int), stream);
    fill_kernel<<<EB, 256, 0, stream>>>(src_wd, dst_wd, off0, cnt,             csr0, NEDGE);
    fill_kernel<<<EB, 256, 0, stream>>>(src_dw, dst_dw, off1, cnt + NNODE,     csr1, NEDGE);
    fill_kernel<<<EB, 256, 0, stream>>>(src_dd, dst_dd, off2, cnt + 2 * NNODE, csr2, NEDGE);

    // ---- weight splits (transposed, hi|lo planes) ----
    {
        dim3 g1((128 * 320 + 255) / 256, 1);
        split_b_kernel<<<g1, 256, 0, stream>>>(Wp_word, WtPw, 300, 128, 320);
        dim3 g2((128 * 128 + 255) / 256, 1);
        split_b_kernel<<<g2, 256, 0, stream>>>(Wp_doc, WtPd, 128, 128, 128);
        dim3 g3((128 * 128 + 255) / 256, 6);
        split_b_kernel<<<g3, 256, 0, stream>>>(Wsrc, WtS, 128, 128, 128);
        split_b_kernel<<<g3, 256, 0, stream>>>(Wdst, WtD, 128, 128, 128);
        dim3 g4((64 * 128 + 255) / 256, 1);
        split_b_kernel<<<g4, 256, 0, stream>>>(Wc1, WtC1, 128, 64, 128);
        dim3 g5((64 * 64 + 255) / 256, 1);
        split_b_kernel<<<g5, 256, 0, stream>>>(Wc2, WtC2, 64, 64, 64);
    }

    auto splitA = [&](const float* X, unsigned short* A2, int K, int Kp) {
        int thr = NNODE * (Kp / 4);
        split_a_kernel<<<(thr + 255) / 256, 256, 0, stream>>>(X, A2, NNODE, K, Kp);
    };
    auto gemm128 = [&](const unsigned short* A2, const unsigned short* Bt,
                       const float* b, float* C, int Kp) {
        gemm_mfma_kernel<128><<<GB, 256, 0, stream>>>(A2, Bt, b, C, NNODE, Kp, 0);
    };

    // ---- input projections ----
    float* hw = hw0; float* hd = hd0; float* hwn = hw1; float* hdn = hd1;
    splitA(x_word, Ax, 300, 320);
    gemm128(Ax, WtPw, bp_word, hw, 320);
    splitA(x_doc, Asd, 128, 128);
    gemm128(Asd, WtPd, bp_doc, hd, 128);

    // ---- 2 GAT layers ----
    for (int l = 0; l < 2; ++l) {
        splitA(hw, Asw, 128, 128);
        splitA(hd, Asd, 128, 128);
        init_acc_kernel<<<(NNODE * 128) / 256, 256, 0, stream>>>(
            hdn, bconv + (l * 3 + 0) * 128, bconv + (l * 3 + 2) * 128, 0.5f, NNODE);
        init_acc_kernel<<<(NNODE * 128) / 256, 256, 0, stream>>>(
            hwn, bconv + (l * 3 + 1) * 128, nullptr, 1.0f, NNODE);

        struct Rel { const unsigned short* as; const unsigned short* ad;
                     const int* off; const int* csr; float* accp; float scl; };
        const Rel rels[3] = {
            { Asw, Asd, off0, csr0, hdn, 0.5f },   // word -> doc
            { Asd, Asw, off1, csr1, hwn, 1.0f },   // doc  -> word
            { Asd, Asd, off2, csr2, hdn, 0.5f },   // doc  -> doc
        };
        for (int r = 0; r < 3; ++r) {
            int idx = l * 3 + r;
            gemm128(rels[r].as, WtS + (size_t)idx * 32768, bsrc + idx * 128, fs, 128);
            gemm128(rels[r].ad, WtD + (size_t)idx * 32768, bdst + idx * 128, fd, 128);
            gat_conv_kernel<<<CB, 256, 0, stream>>>(
                fs, fd, rels[r].off, rels[r].csr, attn + idx * 128,
                rels[r].accp, rels[r].scl, NNODE);
        }
        float* t;
        t = hw; hw = hwn; hwn = t;
        t = hd; hd = hdn; hdn = t;
    }

    // ---- final MLP ----
    splitA(hd, Asd, 128, 128);
    gemm_mfma_kernel<64><<<GB, 256, 0, stream>>>(Asd, WtC1, bc1, z, NNODE, 128, 1);
    splitA(z, Ax, 64, 64);
    gemm_mfma_kernel<64><<<GB, 256, 0, stream>>>(Ax, WtC2, bc2, (float*)d_out, NNODE, 64, 0);
}

// Round 4
// 608.547 us; speedup vs baseline: 1.8897x; 1.3122x over previous
//
#include <hip/hip_runtime.h>

#define NNODE 20000
#define NEDGE 500000

typedef __attribute__((ext_vector_type(8))) short bf16x8;
typedef __attribute__((ext_vector_type(8))) unsigned short u16x8;
typedef __attribute__((ext_vector_type(4))) float f32x4;

__device__ __forceinline__ unsigned short f2bf(float f) {
    unsigned u = __float_as_uint(f);
    return (unsigned short)((u + 0x7FFFu + ((u >> 16) & 1u)) >> 16);
}
__device__ __forceinline__ float bf2f(unsigned short h) {
    return __uint_as_float((unsigned)h << 16);
}

// ---------------------------------------------------------------------------
// split_a: X[M][K] fp32 -> A2[M][2*Kp] bf16 (hi | lo planes), zero-pad K..Kp
// (pad cols may hold junk; they multiply zero-padded B rows, so harmless)
// ---------------------------------------------------------------------------
__global__ __launch_bounds__(256) void split_a_kernel(
    const float* __restrict__ X, unsigned short* __restrict__ A2,
    int M, int K, int Kp)
{
    int i = blockIdx.x * 256 + threadIdx.x;
    int per = Kp >> 2;
    if (i >= M * per) return;
    int r = i / per, c = (i % per) * 4;
    float v[4];
#pragma unroll
    for (int j = 0; j < 4; ++j) v[j] = (c + j < K) ? X[(size_t)r * K + c + j] : 0.f;
    ushort4 hi, lo;
    unsigned short h;
    h = f2bf(v[0]); hi.x = h; lo.x = f2bf(v[0] - bf2f(h));
    h = f2bf(v[1]); hi.y = h; lo.y = f2bf(v[1] - bf2f(h));
    h = f2bf(v[2]); hi.z = h; lo.z = f2bf(v[2] - bf2f(h));
    h = f2bf(v[3]); hi.w = h; lo.w = f2bf(v[3] - bf2f(h));
    *reinterpret_cast<ushort4*>(A2 + (size_t)r * 2 * Kp + c) = hi;
    *reinterpret_cast<ushort4*>(A2 + (size_t)r * 2 * Kp + Kp + c) = lo;
}

// ---------------------------------------------------------------------------
// split_b: B[mat][K][N] fp32 -> Bt[mat][2][NT][Kp] bf16 transposed, cols
// placed at offset nOff (for building concatenated B panels).
// ---------------------------------------------------------------------------
__global__ __launch_bounds__(256) void split_b_kernel(
    const float* __restrict__ B0, unsigned short* __restrict__ Bt0,
    int K, int N, int Kp, int NT, int nOff,
    size_t mStrideB, size_t mStrideT)
{
    int mat = blockIdx.y;
    const float* B = B0 + (size_t)mat * mStrideB;
    unsigned short* Bt = Bt0 + (size_t)mat * mStrideT;
    int i = blockIdx.x * 256 + threadIdx.x;
    if (i >= N * Kp) return;
    int n = i / Kp, k = i % Kp;
    float v = (k < K) ? B[(size_t)k * N + n] : 0.f;
    unsigned short h = f2bf(v);
    size_t o = (size_t)(n + nOff) * Kp + k;
    Bt[o] = h;
    Bt[(size_t)NT * Kp + o] = f2bf(v - bf2f(h));
}

// ---------------------------------------------------------------------------
// Split-bf16 MFMA GEMM: C = Ahi*Bhi + Alo*Bhi + Ahi*Blo  (~fp32 accuracy)
// BM=64, BK=32, 256 thr = 2x2 waves (wave tile 32 x BN/2).
// MODE 0: C0 = f32 [M][BN]
// MODE 1: cat (BN=256): cols<128 -> C0 [M][128] (+b0), cols>=128 -> C1 (+b1)
// MODE 2: S0 = bf16 split [M][2*BN] (hi|lo), optional relu before split
// ---------------------------------------------------------------------------
template<int BN, int MODE>
__global__ __launch_bounds__(256) void gemm_mfma_kernel(
    const unsigned short* __restrict__ A2,   // [M][2*Kp]
    const unsigned short* __restrict__ Bt,   // [2][BN][Kp]
    const float* __restrict__ b0, const float* __restrict__ b1,
    float* __restrict__ C0, float* __restrict__ C1,
    unsigned short* __restrict__ S0,
    int M, int Kp, int do_relu)
{
    constexpr int BM = 64;
    constexpr int FN = BN / 32;
    __shared__ unsigned short As[2][BM][40];
    __shared__ unsigned short Bs[2][BN][40];
    const int tid = threadIdx.x;
    const int m0 = blockIdx.x * BM;
    const int wid = tid >> 6, lane = tid & 63;
    const int wm = wid >> 1, wn = wid & 1;
    const int lr = lane & 15, kg = lane >> 4;

    f32x4 acc[2][FN] = {};
    const size_t KA = 2 * (size_t)Kp;
    const size_t PB = (size_t)BN * Kp;

    for (int k0 = 0; k0 < Kp; k0 += 32) {
        {   // A tile, hi+lo planes
            int row = tid >> 2, ck = tid & 3;
            u16x8 hi = {0,0,0,0,0,0,0,0}, lo = {0,0,0,0,0,0,0,0};
            if (m0 + row < M) {
                const unsigned short* ap = A2 + (size_t)(m0 + row) * KA + k0 + ck * 8;
                hi = *reinterpret_cast<const u16x8*>(ap);
                lo = *reinterpret_cast<const u16x8*>(ap + Kp);
            }
            *reinterpret_cast<u16x8*>(&As[0][row][ck * 8]) = hi;
            *reinterpret_cast<u16x8*>(&As[1][row][ck * 8]) = lo;
        }
#pragma unroll
        for (int it = 0; it < BN / 64; ++it) {   // B tile, hi+lo planes
            int idx = tid + it * 256;
            int nr = idx >> 2, ck = idx & 3;
            const unsigned short* bp = Bt + (size_t)nr * Kp + k0 + ck * 8;
            *reinterpret_cast<u16x8*>(&Bs[0][nr][ck * 8]) =
                *reinterpret_cast<const u16x8*>(bp);
            *reinterpret_cast<u16x8*>(&Bs[1][nr][ck * 8]) =
                *reinterpret_cast<const u16x8*>(bp + PB);
        }
        __syncthreads();
        bf16x8 ah[2], al[2], bh[FN], bl[FN];
#pragma unroll
        for (int fm = 0; fm < 2; ++fm) {
            ah[fm] = *reinterpret_cast<const bf16x8*>(&As[0][wm * 32 + fm * 16 + lr][kg * 8]);
            al[fm] = *reinterpret_cast<const bf16x8*>(&As[1][wm * 32 + fm * 16 + lr][kg * 8]);
        }
#pragma unroll
        for (int fn = 0; fn < FN; ++fn) {
            bh[fn] = *reinterpret_cast<const bf16x8*>(&Bs[0][wn * (BN / 2) + fn * 16 + lr][kg * 8]);
            bl[fn] = *reinterpret_cast<const bf16x8*>(&Bs[1][wn * (BN / 2) + fn * 16 + lr][kg * 8]);
        }
#pragma unroll
        for (int fm = 0; fm < 2; ++fm)
#pragma unroll
            for (int fn = 0; fn < FN; ++fn) {
                acc[fm][fn] = __builtin_amdgcn_mfma_f32_16x16x32_bf16(ah[fm], bh[fn], acc[fm][fn], 0, 0, 0);
                acc[fm][fn] = __builtin_amdgcn_mfma_f32_16x16x32_bf16(al[fm], bh[fn], acc[fm][fn], 0, 0, 0);
                acc[fm][fn] = __builtin_amdgcn_mfma_f32_16x16x32_bf16(ah[fm], bl[fn], acc[fm][fn], 0, 0, 0);
            }
        __syncthreads();
    }
    // epilogue: C/D map: col = lane&15, row = (lane>>4)*4 + j
#pragma unroll
    for (int fm = 0; fm < 2; ++fm)
#pragma unroll
        for (int fn = 0; fn < FN; ++fn) {
            int gc = wn * (BN / 2) + fn * 16 + lr;
            float bv = (MODE == 1) ? (gc < 128 ? b0[gc] : b1[gc - 128]) : b0[gc];
#pragma unroll
            for (int j = 0; j < 4; ++j) {
                int gr = m0 + wm * 32 + fm * 16 + kg * 4 + j;
                if (gr < M) {
                    float v = acc[fm][fn][j] + bv;
                    if (do_relu) v = fmaxf(v, 0.f);
                    if (MODE == 0) {
                        C0[(size_t)gr * BN + gc] = v;
                    } else if (MODE == 1) {
                        if (gc < 128) C0[(size_t)gr * 128 + gc] = v;
                        else          C1[(size_t)gr * 128 + gc - 128] = v;
                    } else {
                        unsigned short h = f2bf(v);
                        S0[(size_t)gr * 2 * BN + gc] = h;
                        S0[(size_t)gr * 2 * BN + BN + gc] = f2bf(v - bf2f(h));
                    }
                }
            }
        }
}

// ---------------------------------------------------------------------------
// CSR build: count -> shfl-scan (3 relations) -> fill
// ---------------------------------------------------------------------------
__global__ __launch_bounds__(256) void count_kernel(
    const int* __restrict__ dst, int* __restrict__ cnt, int n)
{
    int i = blockIdx.x * 256 + threadIdx.x;
    if (i < n) atomicAdd(&cnt[dst[i]], 1);
}

__global__ __launch_bounds__(1024) void scan3_kernel(
    const int* __restrict__ c0, int* __restrict__ o0,
    const int* __restrict__ c1, int* __restrict__ o1,
    const int* __restrict__ c2, int* __restrict__ o2, int n)
{
    const int* cnt = (blockIdx.x == 0) ? c0 : (blockIdx.x == 1) ? c1 : c2;
    int* off       = (blockIdx.x == 0) ? o0 : (blockIdx.x == 1) ? o1 : o2;
    __shared__ int wsum[16];
    __shared__ int s_carry;
    const int tid = threadIdx.x, lane = tid & 63, wid = tid >> 6;
    if (tid == 0) s_carry = 0;
    __syncthreads();
    for (int base = 0; base < n; base += 1024) {
        int i = base + tid;
        int orig = (i < n) ? cnt[i] : 0;
        int v = orig;
#pragma unroll
        for (int s = 1; s < 64; s <<= 1) {
            int t = __shfl_up(v, s);
            if (lane >= s) v += t;
        }
        if (lane == 63) wsum[wid] = v;
        __syncthreads();
        if (wid == 0) {
            int wv = (lane < 16) ? wsum[lane] : 0;
#pragma unroll
            for (int s = 1; s < 16; s <<= 1) {
                int t = __shfl_up(wv, s);
                if (lane >= s) wv += t;
            }
            if (lane < 16) wsum[lane] = wv;
        }
        __syncthreads();
        int carry = s_carry;
        int pre = (wid > 0) ? wsum[wid - 1] : 0;
        if (i < n) off[i] = carry + pre + v - orig;   // exclusive
        __syncthreads();
        if (tid == 1023) s_carry = carry + wsum[15];
        __syncthreads();
    }
    if (tid == 0) off[n] = s_carry;
}

__global__ __launch_bounds__(256) void fill_kernel(
    const int* __restrict__ src, const int* __restrict__ dst,
    const int* __restrict__ off, int* __restrict__ cur,
    int* __restrict__ csrc, int n)
{
    int i = blockIdx.x * 256 + threadIdx.x;
    if (i < n) {
        int d = dst[i];
        int slot = off[d] + atomicAdd(&cur[d], 1);
        csrc[slot] = src[i];
    }
}

__global__ __launch_bounds__(256) void init_acc_kernel(
    float* __restrict__ acc, const float* __restrict__ b1,
    const float* __restrict__ b2, float scale, int nrows)
{
    int i = blockIdx.x * 256 + threadIdx.x;
    if (i < nrows * 128) {
        int j = i & 127;
        float v = b1[j];
        if (b2) v += b2[j];
        acc[i] = v * scale;
    }
}

// ---------------------------------------------------------------------------
// Fused GATv2 conv — single pass, 4-edge unrolled online softmax.
// 32 lanes = one dst row; lane owns elems 4l..4l+3; head = l/8.
// Optionally emits the final accumulated row as bf16 hi|lo split (sp).
// ---------------------------------------------------------------------------
#define EDGE_SCORE(u, p)                                                   \
    {                                                                      \
        float4 v;                                                          \
        v.x = u.x + fdv.x; v.y = u.y + fdv.y;                              \
        v.z = u.z + fdv.z; v.w = u.w + fdv.w;                              \
        v.x = v.x > 0.f ? v.x : 0.2f * v.x;                                \
        v.y = v.y > 0.f ? v.y : 0.2f * v.y;                                \
        v.z = v.z > 0.f ? v.z : 0.2f * v.z;                                \
        v.w = v.w > 0.f ? v.w : 0.2f * v.w;                                \
        p = v.x * av.x + v.y * av.y + v.z * av.z + v.w * av.w;             \
        p += __shfl_xor(p, 1);                                             \
        p += __shfl_xor(p, 2);                                             \
        p += __shfl_xor(p, 4);                                             \
    }

__global__ __launch_bounds__(256) void gat_conv_kernel(
    const float* __restrict__ fs, const float* __restrict__ fd,
    const int* __restrict__ off, const int* __restrict__ csrc,
    const float* __restrict__ attn, float* __restrict__ acc,
    unsigned short* __restrict__ sp, float scale, int n_dst)
{
    int gid = blockIdx.x * 256 + threadIdx.x;
    int d = gid >> 5;
    int lane = gid & 31;
    if (d >= n_dst) return;
    const int e0 = off[d], e1 = off[d + 1];
    const float4* fs4 = reinterpret_cast<const float4*>(fs);
    const float4 fdv = reinterpret_cast<const float4*>(fd)[(size_t)d * 32 + lane];
    const float4 av  = reinterpret_cast<const float4*>(attn)[lane];

    float mx = -3.0e38f, ssum = 0.f;
    float4 a4 = make_float4(0.f, 0.f, 0.f, 0.f);
    int i = e0;
    for (; i + 4 <= e1; i += 4) {
        int s0 = csrc[i], s1 = csrc[i + 1], s2 = csrc[i + 2], s3 = csrc[i + 3];
        float4 u0 = fs4[(size_t)s0 * 32 + lane];
        float4 u1 = fs4[(size_t)s1 * 32 + lane];
        float4 u2 = fs4[(size_t)s2 * 32 + lane];
        float4 u3 = fs4[(size_t)s3 * 32 + lane];
        float p0, p1, p2, p3;
        EDGE_SCORE(u0, p0); EDGE_SCORE(u1, p1);
        EDGE_SCORE(u2, p2); EDGE_SCORE(u3, p3);
        float mnew = fmaxf(fmaxf(fmaxf(p0, p1), fmaxf(p2, p3)), mx);
        float f  = __expf(mx - mnew);
        float w0 = __expf(p0 - mnew), w1 = __expf(p1 - mnew);
        float w2 = __expf(p2 - mnew), w3 = __expf(p3 - mnew);
        ssum = ssum * f + ((w0 + w1) + (w2 + w3));
        a4.x = a4.x * f + w0 * u0.x + w1 * u1.x + w2 * u2.x + w3 * u3.x;
        a4.y = a4.y * f + w0 * u0.y + w1 * u1.y + w2 * u2.y + w3 * u3.y;
        a4.z = a4.z * f + w0 * u0.z + w1 * u1.z + w2 * u2.z + w3 * u3.z;
        a4.w = a4.w * f + w0 * u0.w + w1 * u1.w + w2 * u2.w + w3 * u3.w;
        mx = mnew;
    }
    for (; i < e1; ++i) {
        int s0 = csrc[i];
        float4 u0 = fs4[(size_t)s0 * 32 + lane];
        float p0;
        EDGE_SCORE(u0, p0);
        float mnew = fmaxf(mx, p0);
        float f = __expf(mx - mnew);
        float w = __expf(p0 - mnew);
        ssum = ssum * f + w;
        a4.x = a4.x * f + w * u0.x;
        a4.y = a4.y * f + w * u0.y;
        a4.z = a4.z * f + w * u0.z;
        a4.w = a4.w * f + w * u0.w;
        mx = mnew;
    }
    float rs = (ssum > 0.f) ? scale / ssum : 0.f;
    float* op = acc + (size_t)d * 128 + lane * 4;
    float4 cur = *reinterpret_cast<float4*>(op);
    cur.x += rs * a4.x; cur.y += rs * a4.y;
    cur.z += rs * a4.z; cur.w += rs * a4.w;
    *reinterpret_cast<float4*>(op) = cur;
    if (sp) {
        ushort4 hi, lo;
        unsigned short h;
        h = f2bf(cur.x); hi.x = h; lo.x = f2bf(cur.x - bf2f(h));
        h = f2bf(cur.y); hi.y = h; lo.y = f2bf(cur.y - bf2f(h));
        h = f2bf(cur.z); hi.z = h; lo.z = f2bf(cur.z - bf2f(h));
        h = f2bf(cur.w); hi.w = h; lo.w = f2bf(cur.w - bf2f(h));
        *reinterpret_cast<ushort4*>(sp + (size_t)d * 256 + lane * 4) = hi;
        *reinterpret_cast<ushort4*>(sp + (size_t)d * 256 + 128 + lane * 4) = lo;
    }
}

// ---------------------------------------------------------------------------
extern "C" void kernel_launch(void* const* d_in, const int* in_sizes, int n_in,
                              void* d_out, int out_size, void* d_ws, size_t ws_size,
                              hipStream_t stream)
{
    const float* x_word  = (const float*)d_in[0];
    const float* x_doc   = (const float*)d_in[1];
    const float* Wp_word = (const float*)d_in[2];
    const float* bp_word = (const float*)d_in[3];
    const float* Wp_doc  = (const float*)d_in[4];
    const float* bp_doc  = (const float*)d_in[5];
    const float* Wsrc    = (const float*)d_in[6];
    const float* bsrc    = (const float*)d_in[7];
    const float* Wdst    = (const float*)d_in[8];
    const float* bdst    = (const float*)d_in[9];
    const float* attn    = (const float*)d_in[10];
    const float* bconv   = (const float*)d_in[11];
    const float* Wc1     = (const float*)d_in[12];
    const float* bc1     = (const float*)d_in[13];
    const float* Wc2     = (const float*)d_in[14];
    const float* bc2     = (const float*)d_in[15];
    const int* src_wd = (const int*)d_in[16];
    const int* dst_wd = (const int*)d_in[17];
    const int* src_dw = (const int*)d_in[18];
    const int* dst_dw = (const int*)d_in[19];
    const int* src_dd = (const int*)d_in[20];
    const int* dst_dd = (const int*)d_in[21];

    // ---- workspace layout ----
    // floats: b0..b3 (feature panels), hdn, hwn  = 6*NF
    // overlays: Ax (x_word split) on b0.. (dead before b0 written);
    //           Axd (x_doc split) on b3; Az (MLP z split) on AswB.
    const size_t NF = (size_t)NNODE * 128;          // 2.56M
    float* F  = (float*)d_ws;
    float* b0f = F;                 // fs_wd / fs_dd
    float* b1f = F + 1 * NF;        // fd_dw
    float* b2f = F + 2 * NF;        // fd_wd / fd_dd
    float* b3f = F + 3 * NF;        // fs_dw
    float* hdn = F + 4 * NF;
    float* hwn = F + 5 * NF;
    unsigned short* Ax  = (unsigned short*)b0f;   // 20000*640 u16 = 2.5*NF floats
    unsigned short* Axd = (unsigned short*)b3f;   // 20000*256 u16 = 1.0*NF floats
    unsigned short* U = (unsigned short*)(F + 6 * NF);
    unsigned short* AswA = U;                        // 20000*256 each
    unsigned short* AsdA = AswA + (size_t)NNODE * 256;
    unsigned short* AswB = AsdA + (size_t)NNODE * 256;
    unsigned short* AsdB = AswB + (size_t)NNODE * 256;
    unsigned short* WtPw  = AsdB + (size_t)NNODE * 256;  // 2*128*320
    unsigned short* WtPd  = WtPw + 81920;                // 2*128*128
    unsigned short* WtCat = WtPd + 32768;                // 2 layers * 3 cats * 2*256*128
    unsigned short* WtC1  = WtCat + 393216;              // 2*64*128
    unsigned short* WtC2  = WtC1 + 16384;                // 2*64*64
    unsigned short* Az    = AswB;                        // overlay (dead by MLP time)
    int* I    = (int*)(WtC2 + 8192);
    int* cnt  = I;
    int* off0 = I + 3 * NNODE;
    int* off1 = off0 + 20004;
    int* off2 = off1 + 20004;
    int* csr0 = off2 + 20004;
    int* csr1 = csr0 + NEDGE;
    int* csr2 = csr1 + NEDGE;

    const int EB = (NEDGE + 255) / 256;
    const int GB = (NNODE + 63) / 64;
    const int CB = (NNODE * 32) / 256;

    // ---- CSR build ----
    (void)hipMemsetAsync(cnt, 0, 3 * NNODE * sizeof(int), stream);
    count_kernel<<<EB, 256, 0, stream>>>(dst_wd, cnt,             NEDGE);
    count_kernel<<<EB, 256, 0, stream>>>(dst_dw, cnt + NNODE,     NEDGE);
    count_kernel<<<EB, 256, 0, stream>>>(dst_dd, cnt + 2 * NNODE, NEDGE);
    scan3_kernel<<<3, 1024, 0, stream>>>(cnt, off0, cnt + NNODE, off1,
                                         cnt + 2 * NNODE, off2, NNODE);
    (void)hipMemsetAsync(cnt, 0, 3 * NNODE * sizeof(int), stream);
    fill_kernel<<<EB, 256, 0, stream>>>(src_wd, dst_wd, off0, cnt,             csr0, NEDGE);
    fill_kernel<<<EB, 256, 0, stream>>>(src_dw, dst_dw, off1, cnt + NNODE,     csr1, NEDGE);
    fill_kernel<<<EB, 256, 0, stream>>>(src_dd, dst_dd, off2, cnt + 2 * NNODE, csr2, NEDGE);

    // ---- weight splits ----
    split_b_kernel<<<dim3((128 * 320 + 255) / 256, 1), 256, 0, stream>>>(
        Wp_word, WtPw, 300, 128, 320, 128, 0, 0, 0);
    split_b_kernel<<<dim3((128 * 128 + 255) / 256, 1), 256, 0, stream>>>(
        Wp_doc, WtPd, 128, 128, 128, 128, 0, 0, 0);
    // cat panels per layer l (grid.y = l, strides 3*16384 / 3*65536):
    //   cat0 (A=h_w): [Wsrc(l,0) | Wdst(l,1)]
    //   cat1 (A=h_d): [Wdst(l,0) | Wsrc(l,1)]
    //   cat2 (A=h_d): [Wsrc(l,2) | Wdst(l,2)]
    {
        dim3 g(64, 2);
        split_b_kernel<<<g, 256, 0, stream>>>(Wsrc,         WtCat,          128, 128, 128, 256,   0, 49152, 196608);
        split_b_kernel<<<g, 256, 0, stream>>>(Wdst + 16384, WtCat,          128, 128, 128, 256, 128, 49152, 196608);
        split_b_kernel<<<g, 256, 0, stream>>>(Wdst,         WtCat + 65536,  128, 128, 128, 256,   0, 49152, 196608);
        split_b_kernel<<<g, 256, 0, stream>>>(Wsrc + 16384, WtCat + 65536,  128, 128, 128, 256, 128, 49152, 196608);
        split_b_kernel<<<g, 256, 0, stream>>>(Wsrc + 32768, WtCat + 131072, 128, 128, 128, 256,   0, 49152, 196608);
        split_b_kernel<<<g, 256, 0, stream>>>(Wdst + 32768, WtCat + 131072, 128, 128, 128, 256, 128, 49152, 196608);
    }
    split_b_kernel<<<dim3((64 * 128 + 255) / 256, 1), 256, 0, stream>>>(
        Wc1, WtC1, 128, 64, 128, 64, 0, 0, 0);
    split_b_kernel<<<dim3((64 * 64 + 255) / 256, 1), 256, 0, stream>>>(
        Wc2, WtC2, 64, 64, 64, 64, 0, 0, 0);

    // ---- x splits + projections (emit split h directly) ----
    split_a_kernel<<<(NNODE * 80 + 255) / 256, 256, 0, stream>>>(x_word, Ax, NNODE, 300, 320);
    split_a_kernel<<<(NNODE * 32 + 255) / 256, 256, 0, stream>>>(x_doc, Axd, NNODE, 128, 128);
    gemm_mfma_kernel<128, 2><<<GB, 256, 0, stream>>>(
        Ax, WtPw, bp_word, nullptr, nullptr, nullptr, AswA, NNODE, 320, 0);
    gemm_mfma_kernel<128, 2><<<GB, 256, 0, stream>>>(
        Axd, WtPd, bp_doc, nullptr, nullptr, nullptr, AsdA, NNODE, 128, 0);
    // Ax/Axd (= b0..b3 float region) dead from here on.

    // ---- 2 GAT layers ----
    const unsigned short* Asw_in = AswA;
    const unsigned short* Asd_in = AsdA;
    for (int l = 0; l < 2; ++l) {
        const size_t cb = (size_t)l * 196608;
        init_acc_kernel<<<(NNODE * 128) / 256, 256, 0, stream>>>(
            hdn, bconv + (l * 3 + 0) * 128, bconv + (l * 3 + 2) * 128, 0.5f, NNODE);
        init_acc_kernel<<<(NNODE * 128) / 256, 256, 0, stream>>>(
            hwn, bconv + (l * 3 + 1) * 128, nullptr, 1.0f, NNODE);

        // gemm_w: [fs_wd | fd_dw] = h_w @ [Wsrc0|Wdst1]
        gemm_mfma_kernel<256, 1><<<GB, 256, 0, stream>>>(
            Asw_in, WtCat + cb,
            bsrc + (l * 3 + 0) * 128, bdst + (l * 3 + 1) * 128,
            b0f, b1f, nullptr, NNODE, 128, 0);
        // gemm_d1: [fd_wd | fs_dw] = h_d @ [Wdst0|Wsrc1]
        gemm_mfma_kernel<256, 1><<<GB, 256, 0, stream>>>(
            Asd_in, WtCat + cb + 65536,
            bdst + (l * 3 + 0) * 128, bsrc + (l * 3 + 1) * 128,
            b2f, b3f, nullptr, NNODE, 128, 0);
        // conv rel0 (word->doc): fs=b0f, fd=b2f
        gat_conv_kernel<<<CB, 256, 0, stream>>>(
            b0f, b2f, off0, csr0, attn + (l * 3 + 0) * 128,
            hdn, nullptr, 0.5f, NNODE);
        // conv rel1 (doc->word): fs=b3f, fd=b1f
        gat_conv_kernel<<<CB, 256, 0, stream>>>(
            b3f, b1f, off1, csr1, attn + (l * 3 + 1) * 128,
            hwn, (l == 0 ? AswB : nullptr), 1.0f, NNODE);
        // gemm_d2: [fs_dd | fd_dd] = h_d @ [Wsrc2|Wdst2]  (reuse b0f/b2f)
        gemm_mfma_kernel<256, 1><<<GB, 256, 0, stream>>>(
            Asd_in, WtCat + cb + 131072,
            bsrc + (l * 3 + 2) * 128, bdst + (l * 3 + 2) * 128,
            b0f, b2f, nullptr, NNODE, 128, 0);
        // conv rel2 (doc->doc): fs=b0f, fd=b2f; emits split of final h_d
        gat_conv_kernel<<<CB, 256, 0, stream>>>(
            b0f, b2f, off2, csr2, attn + (l * 3 + 2) * 128,
            hdn, (l == 0 ? AsdB : AsdA), 0.5f, NNODE);

        Asw_in = AswB;
        Asd_in = AsdB;
    }

    // ---- final MLP: z = relu(hd @ Wc1 + bc1) (split); out = z @ Wc2 + bc2 ----
    gemm_mfma_kernel<64, 2><<<GB, 256, 0, stream>>>(
        AsdA, WtC1, bc1, nullptr, nullptr, nullptr, Az, NNODE, 128, 1);
    gemm_mfma_kernel<64, 0><<<GB, 256, 0, stream>>>(
        Az, WtC2, bc2, nullptr, (float*)d_out, nullptr, nullptr, NNODE, 64, 0);
}

// Round 5
// 485.377 us; speedup vs baseline: 2.3693x; 1.2538x over previous
//
#include <hip/hip_runtime.h>

#define NNODE 20000
#define NEDGE 500000

typedef __attribute__((ext_vector_type(8))) short bf16x8;
typedef __attribute__((ext_vector_type(8))) unsigned short u16x8;
typedef __attribute__((ext_vector_type(4))) float f32x4;

__device__ __forceinline__ unsigned short f2bf(float f) {
    unsigned u = __float_as_uint(f);
    return (unsigned short)((u + 0x7FFFu + ((u >> 16) & 1u)) >> 16);
}
__device__ __forceinline__ float bf2f(unsigned short h) {
    return __uint_as_float((unsigned)h << 16);
}

// ---------------------------------------------------------------------------
// split_a: X[M][K] fp32 -> A2[M][2*Kp] bf16 (hi | lo planes), zero-pad K..Kp
// ---------------------------------------------------------------------------
__global__ __launch_bounds__(256) void split_a_kernel(
    const float* __restrict__ X, unsigned short* __restrict__ A2,
    int M, int K, int Kp)
{
    int i = blockIdx.x * 256 + threadIdx.x;
    int per = Kp >> 2;
    if (i >= M * per) return;
    int r = i / per, c = (i % per) * 4;
    float v[4];
#pragma unroll
    for (int j = 0; j < 4; ++j) v[j] = (c + j < K) ? X[(size_t)r * K + c + j] : 0.f;
    ushort4 hi, lo;
    unsigned short h;
    h = f2bf(v[0]); hi.x = h; lo.x = f2bf(v[0] - bf2f(h));
    h = f2bf(v[1]); hi.y = h; lo.y = f2bf(v[1] - bf2f(h));
    h = f2bf(v[2]); hi.z = h; lo.z = f2bf(v[2] - bf2f(h));
    h = f2bf(v[3]); hi.w = h; lo.w = f2bf(v[3] - bf2f(h));
    *reinterpret_cast<ushort4*>(A2 + (size_t)r * 2 * Kp + c) = hi;
    *reinterpret_cast<ushort4*>(A2 + (size_t)r * 2 * Kp + Kp + c) = lo;
}

// ---------------------------------------------------------------------------
// split_b: B[K][N] fp32 -> Bt[2][N][Kp] bf16 transposed (single matrix)
// ---------------------------------------------------------------------------
__global__ __launch_bounds__(256) void split_b_kernel(
    const float* __restrict__ B, unsigned short* __restrict__ Bt,
    int K, int N, int Kp)
{
    int i = blockIdx.x * 256 + threadIdx.x;
    if (i >= N * Kp) return;
    int n = i / Kp, k = i % Kp;
    float v = (k < K) ? B[(size_t)k * N + n] : 0.f;
    unsigned short h = f2bf(v);
    Bt[i] = h;
    Bt[(size_t)N * Kp + i] = f2bf(v - bf2f(h));
}

// ---------------------------------------------------------------------------
// split_cat: build all 6 cat panels WtCat[l*3+c] = [2][256][128] from
//   c0: [Wsrc(l,0) | Wdst(l,1)]  c1: [Wdst(l,0) | Wsrc(l,1)]
//   c2: [Wsrc(l,2) | Wdst(l,2)]
// ---------------------------------------------------------------------------
__global__ __launch_bounds__(256) void split_cat_kernel(
    const float* __restrict__ Wsrc, const float* __restrict__ Wdst,
    unsigned short* __restrict__ WtCat)
{
    int i = blockIdx.x * 256 + threadIdx.x;   // over 6*256*128
    if (i >= 6 * 256 * 128) return;
    int lc = i / (256 * 128);
    int rem = i % (256 * 128);
    int n = rem / 128, k = rem % 128;
    int l = lc / 3, c = lc % 3;
    int half = n >> 7, nn = n & 127;
    const float* M;
    if (c == 0) M = half ? (Wdst + (size_t)(l * 3 + 1) * 16384) : (Wsrc + (size_t)(l * 3 + 0) * 16384);
    else if (c == 1) M = half ? (Wsrc + (size_t)(l * 3 + 1) * 16384) : (Wdst + (size_t)(l * 3 + 0) * 16384);
    else M = half ? (Wdst + (size_t)(l * 3 + 2) * 16384) : (Wsrc + (size_t)(l * 3 + 2) * 16384);
    float v = M[(size_t)k * 128 + nn];
    unsigned short h = f2bf(v);
    unsigned short* Bt = WtCat + (size_t)lc * 65536;
    Bt[(size_t)n * 128 + k] = h;
    Bt[32768 + (size_t)n * 128 + k] = f2bf(v - bf2f(h));
}

// ---------------------------------------------------------------------------
// Split-bf16 MFMA GEMM (proj / MLP): C = Ahi*Bhi + Alo*Bhi + Ahi*Blo
// MODE 0: C0 = f32 [M][BN];  MODE 2: S0 = bf16 split [M][2*BN], opt. relu
// ---------------------------------------------------------------------------
template<int BN, int MODE>
__global__ __launch_bounds__(256) void gemm_mfma_kernel(
    const unsigned short* __restrict__ A2,   // [M][2*Kp]
    const unsigned short* __restrict__ Bt,   // [2][BN][Kp]
    const float* __restrict__ b0,
    float* __restrict__ C0, unsigned short* __restrict__ S0,
    int M, int Kp, int do_relu)
{
    constexpr int BM = 64;
    constexpr int FN = BN / 32;
    __shared__ unsigned short As[2][BM][40];
    __shared__ unsigned short Bs[2][BN][40];
    const int tid = threadIdx.x;
    const int m0 = blockIdx.x * BM;
    const int wid = tid >> 6, lane = tid & 63;
    const int wm = wid >> 1, wn = wid & 1;
    const int lr = lane & 15, kg = lane >> 4;

    f32x4 acc[2][FN] = {};
    const size_t KA = 2 * (size_t)Kp;
    const size_t PB = (size_t)BN * Kp;

    for (int k0 = 0; k0 < Kp; k0 += 32) {
        {
            int row = tid >> 2, ck = tid & 3;
            u16x8 hi = {0,0,0,0,0,0,0,0}, lo = {0,0,0,0,0,0,0,0};
            if (m0 + row < M) {
                const unsigned short* ap = A2 + (size_t)(m0 + row) * KA + k0 + ck * 8;
                hi = *reinterpret_cast<const u16x8*>(ap);
                lo = *reinterpret_cast<const u16x8*>(ap + Kp);
            }
            *reinterpret_cast<u16x8*>(&As[0][row][ck * 8]) = hi;
            *reinterpret_cast<u16x8*>(&As[1][row][ck * 8]) = lo;
        }
#pragma unroll
        for (int it = 0; it < BN / 64; ++it) {
            int idx = tid + it * 256;
            int nr = idx >> 2, ck = idx & 3;
            const unsigned short* bp = Bt + (size_t)nr * Kp + k0 + ck * 8;
            *reinterpret_cast<u16x8*>(&Bs[0][nr][ck * 8]) = *reinterpret_cast<const u16x8*>(bp);
            *reinterpret_cast<u16x8*>(&Bs[1][nr][ck * 8]) = *reinterpret_cast<const u16x8*>(bp + PB);
        }
        __syncthreads();
        bf16x8 ah[2], al[2], bh[FN], bl[FN];
#pragma unroll
        for (int fm = 0; fm < 2; ++fm) {
            ah[fm] = *reinterpret_cast<const bf16x8*>(&As[0][wm * 32 + fm * 16 + lr][kg * 8]);
            al[fm] = *reinterpret_cast<const bf16x8*>(&As[1][wm * 32 + fm * 16 + lr][kg * 8]);
        }
#pragma unroll
        for (int fn = 0; fn < FN; ++fn) {
            bh[fn] = *reinterpret_cast<const bf16x8*>(&Bs[0][wn * (BN / 2) + fn * 16 + lr][kg * 8]);
            bl[fn] = *reinterpret_cast<const bf16x8*>(&Bs[1][wn * (BN / 2) + fn * 16 + lr][kg * 8]);
        }
#pragma unroll
        for (int fm = 0; fm < 2; ++fm)
#pragma unroll
            for (int fn = 0; fn < FN; ++fn) {
                acc[fm][fn] = __builtin_amdgcn_mfma_f32_16x16x32_bf16(ah[fm], bh[fn], acc[fm][fn], 0, 0, 0);
                acc[fm][fn] = __builtin_amdgcn_mfma_f32_16x16x32_bf16(al[fm], bh[fn], acc[fm][fn], 0, 0, 0);
                acc[fm][fn] = __builtin_amdgcn_mfma_f32_16x16x32_bf16(ah[fm], bl[fn], acc[fm][fn], 0, 0, 0);
            }
        __syncthreads();
    }
#pragma unroll
    for (int fm = 0; fm < 2; ++fm)
#pragma unroll
        for (int fn = 0; fn < FN; ++fn) {
            int gc = wn * (BN / 2) + fn * 16 + lr;
            float bv = b0[gc];
#pragma unroll
            for (int j = 0; j < 4; ++j) {
                int gr = m0 + wm * 32 + fm * 16 + kg * 4 + j;
                if (gr < M) {
                    float v = acc[fm][fn][j] + bv;
                    if (do_relu) v = fmaxf(v, 0.f);
                    if (MODE == 0) {
                        C0[(size_t)gr * BN + gc] = v;
                    } else {
                        unsigned short h = f2bf(v);
                        S0[(size_t)gr * 2 * BN + gc] = h;
                        S0[(size_t)gr * 2 * BN + BN + gc] = f2bf(v - bf2f(h));
                    }
                }
            }
        }
}

// ---------------------------------------------------------------------------
// Batched cat GEMM (grid.y selects one of 3): BN=256, Kp=128, bf16 outputs
// to two 128-col panels.
// ---------------------------------------------------------------------------
struct Cat3Args {
    const unsigned short* A[3];
    const unsigned short* Bt[3];
    const float* bs0[3];
    const float* bs1[3];
    unsigned short* P0[3];
    unsigned short* P1[3];
};

__global__ __launch_bounds__(256) void gemm_cat3_kernel(Cat3Args args, int M)
{
    constexpr int BN = 256, BM = 64, FN = 8, Kp = 128;
    const int y = blockIdx.y;
    const unsigned short* __restrict__ A2 = args.A[y];
    const unsigned short* __restrict__ Bt = args.Bt[y];
    __shared__ unsigned short As[2][BM][40];
    __shared__ unsigned short Bs[2][BN][40];
    const int tid = threadIdx.x;
    const int m0 = blockIdx.x * BM;
    const int wid = tid >> 6, lane = tid & 63;
    const int wm = wid >> 1, wn = wid & 1;
    const int lr = lane & 15, kg = lane >> 4;

    f32x4 acc[2][FN] = {};
    const size_t KA = 2 * (size_t)Kp;
    const size_t PB = (size_t)BN * Kp;

    for (int k0 = 0; k0 < Kp; k0 += 32) {
        {
            int row = tid >> 2, ck = tid & 3;
            u16x8 hi = {0,0,0,0,0,0,0,0}, lo = {0,0,0,0,0,0,0,0};
            if (m0 + row < M) {
                const unsigned short* ap = A2 + (size_t)(m0 + row) * KA + k0 + ck * 8;
                hi = *reinterpret_cast<const u16x8*>(ap);
                lo = *reinterpret_cast<const u16x8*>(ap + Kp);
            }
            *reinterpret_cast<u16x8*>(&As[0][row][ck * 8]) = hi;
            *reinterpret_cast<u16x8*>(&As[1][row][ck * 8]) = lo;
        }
#pragma unroll
        for (int it = 0; it < 4; ++it) {
            int idx = tid + it * 256;
            int nr = idx >> 2, ck = idx & 3;
            const unsigned short* bp = Bt + (size_t)nr * Kp + k0 + ck * 8;
            *reinterpret_cast<u16x8*>(&Bs[0][nr][ck * 8]) = *reinterpret_cast<const u16x8*>(bp);
            *reinterpret_cast<u16x8*>(&Bs[1][nr][ck * 8]) = *reinterpret_cast<const u16x8*>(bp + PB);
        }
        __syncthreads();
        bf16x8 ah[2], al[2], bh[FN], bl[FN];
#pragma unroll
        for (int fm = 0; fm < 2; ++fm) {
            ah[fm] = *reinterpret_cast<const bf16x8*>(&As[0][wm * 32 + fm * 16 + lr][kg * 8]);
            al[fm] = *reinterpret_cast<const bf16x8*>(&As[1][wm * 32 + fm * 16 + lr][kg * 8]);
        }
#pragma unroll
        for (int fn = 0; fn < FN; ++fn) {
            bh[fn] = *reinterpret_cast<const bf16x8*>(&Bs[0][wn * 128 + fn * 16 + lr][kg * 8]);
            bl[fn] = *reinterpret_cast<const bf16x8*>(&Bs[1][wn * 128 + fn * 16 + lr][kg * 8]);
        }
#pragma unroll
        for (int fm = 0; fm < 2; ++fm)
#pragma unroll
            for (int fn = 0; fn < FN; ++fn) {
                acc[fm][fn] = __builtin_amdgcn_mfma_f32_16x16x32_bf16(ah[fm], bh[fn], acc[fm][fn], 0, 0, 0);
                acc[fm][fn] = __builtin_amdgcn_mfma_f32_16x16x32_bf16(al[fm], bh[fn], acc[fm][fn], 0, 0, 0);
                acc[fm][fn] = __builtin_amdgcn_mfma_f32_16x16x32_bf16(ah[fm], bl[fn], acc[fm][fn], 0, 0, 0);
            }
        __syncthreads();
    }
    const float* __restrict__ bs0 = args.bs0[y];
    const float* __restrict__ bs1 = args.bs1[y];
    unsigned short* __restrict__ P0 = args.P0[y];
    unsigned short* __restrict__ P1 = args.P1[y];
#pragma unroll
    for (int fm = 0; fm < 2; ++fm)
#pragma unroll
        for (int fn = 0; fn < FN; ++fn) {
            int gc = wn * 128 + fn * 16 + lr;
            float bv = (gc < 128) ? bs0[gc] : bs1[gc - 128];
#pragma unroll
            for (int j = 0; j < 4; ++j) {
                int gr = m0 + wm * 32 + fm * 16 + kg * 4 + j;
                if (gr < M) {
                    float v = acc[fm][fn][j] + bv;
                    unsigned short h = f2bf(v);
                    if (gc < 128) P0[(size_t)gr * 128 + gc] = h;
                    else          P1[(size_t)gr * 128 + gc - 128] = h;
                }
            }
        }
}

// ---------------------------------------------------------------------------
// CSR build: fused count (3 rels) -> shfl-scan -> fused fill (3 rels)
// ---------------------------------------------------------------------------
__global__ __launch_bounds__(256) void count3_kernel(
    const int* __restrict__ d0, const int* __restrict__ d1,
    const int* __restrict__ d2, int* __restrict__ cnt, int n)
{
    int i = blockIdx.x * 256 + threadIdx.x;
    if (i < n) atomicAdd(&cnt[d0[i]], 1);
    else if (i < 2 * n) atomicAdd(&cnt[NNODE + d1[i - n]], 1);
    else if (i < 3 * n) atomicAdd(&cnt[2 * NNODE + d2[i - 2 * n]], 1);
}

__global__ __launch_bounds__(1024) void scan3_kernel(
    const int* __restrict__ c0, int* __restrict__ o0,
    const int* __restrict__ c1, int* __restrict__ o1,
    const int* __restrict__ c2, int* __restrict__ o2, int n)
{
    const int* cnt = (blockIdx.x == 0) ? c0 : (blockIdx.x == 1) ? c1 : c2;
    int* off       = (blockIdx.x == 0) ? o0 : (blockIdx.x == 1) ? o1 : o2;
    __shared__ int wsum[16];
    __shared__ int s_carry;
    const int tid = threadIdx.x, lane = tid & 63, wid = tid >> 6;
    if (tid == 0) s_carry = 0;
    __syncthreads();
    for (int base = 0; base < n; base += 1024) {
        int i = base + tid;
        int orig = (i < n) ? cnt[i] : 0;
        int v = orig;
#pragma unroll
        for (int s = 1; s < 64; s <<= 1) {
            int t = __shfl_up(v, s);
            if (lane >= s) v += t;
        }
        if (lane == 63) wsum[wid] = v;
        __syncthreads();
        if (wid == 0) {
            int wv = (lane < 16) ? wsum[lane] : 0;
#pragma unroll
            for (int s = 1; s < 16; s <<= 1) {
                int t = __shfl_up(wv, s);
                if (lane >= s) wv += t;
            }
            if (lane < 16) wsum[lane] = wv;
        }
        __syncthreads();
        int carry = s_carry;
        int pre = (wid > 0) ? wsum[wid - 1] : 0;
        if (i < n) off[i] = carry + pre + v - orig;
        __syncthreads();
        if (tid == 1023) s_carry = carry + wsum[15];
        __syncthreads();
    }
    if (tid == 0) off[n] = s_carry;
}

__global__ __launch_bounds__(256) void fill3_kernel(
    const int* __restrict__ s0, const int* __restrict__ d0,
    const int* __restrict__ s1, const int* __restrict__ d1,
    const int* __restrict__ s2, const int* __restrict__ d2,
    const int* __restrict__ off0, const int* __restrict__ off1,
    const int* __restrict__ off2,
    int* __restrict__ cur, int* __restrict__ csr, int n)
{
    int i = blockIdx.x * 256 + threadIdx.x;
    if (i < n) {
        int d = d0[i];
        csr[off0[d] + atomicAdd(&cur[d], 1)] = s0[i];
    } else if (i < 2 * n) {
        int k = i - n;
        int d = d1[k];
        csr[NEDGE + off1[d] + atomicAdd(&cur[NNODE + d], 1)] = s1[k];
    } else if (i < 3 * n) {
        int k = i - 2 * n;
        int d = d2[k];
        csr[2 * NEDGE + off2[d] + atomicAdd(&cur[2 * NNODE + d], 1)] = s2[k];
    }
}

// ---------------------------------------------------------------------------
// GATv2 conv over one relation, bf16 panels, 16-lane groups (lane owns 8 cols)
// Adds wscale * softmax-weighted-sum into out[8].
// ---------------------------------------------------------------------------
__device__ __forceinline__ void rel_accum(
    const unsigned short* __restrict__ fsP,
    const unsigned short* __restrict__ fdP,
    const int* __restrict__ off, const int* __restrict__ csrc,
    const float* __restrict__ attnRow,
    int d, int lane, float wscale, float* __restrict__ out)
{
    const int e0 = off[d], e1 = off[d + 1];
    float fdv[8], av[8];
    {
        u16x8 t = *reinterpret_cast<const u16x8*>(fdP + (size_t)d * 128 + lane * 8);
#pragma unroll
        for (int j = 0; j < 8; ++j) fdv[j] = bf2f(t[j]);
    }
#pragma unroll
    for (int j = 0; j < 8; ++j) av[j] = attnRow[lane * 8 + j];

    float mx = -3.0e38f, ssum = 0.f;
    float acc[8];
#pragma unroll
    for (int j = 0; j < 8; ++j) acc[j] = 0.f;

    int i = e0;
    for (; i + 4 <= e1; i += 4) {
        int s0 = csrc[i], s1 = csrc[i + 1], s2 = csrc[i + 2], s3 = csrc[i + 3];
        u16x8 q0 = *reinterpret_cast<const u16x8*>(fsP + (size_t)s0 * 128 + lane * 8);
        u16x8 q1 = *reinterpret_cast<const u16x8*>(fsP + (size_t)s1 * 128 + lane * 8);
        u16x8 q2 = *reinterpret_cast<const u16x8*>(fsP + (size_t)s2 * 128 + lane * 8);
        u16x8 q3 = *reinterpret_cast<const u16x8*>(fsP + (size_t)s3 * 128 + lane * 8);
        float u0[8], u1[8], u2[8], u3[8];
        float p0 = 0.f, p1 = 0.f, p2 = 0.f, p3 = 0.f;
#pragma unroll
        for (int j = 0; j < 8; ++j) {
            u0[j] = bf2f(q0[j]); float v = u0[j] + fdv[j]; v = v > 0.f ? v : 0.2f * v; p0 += v * av[j];
        }
#pragma unroll
        for (int j = 0; j < 8; ++j) {
            u1[j] = bf2f(q1[j]); float v = u1[j] + fdv[j]; v = v > 0.f ? v : 0.2f * v; p1 += v * av[j];
        }
#pragma unroll
        for (int j = 0; j < 8; ++j) {
            u2[j] = bf2f(q2[j]); float v = u2[j] + fdv[j]; v = v > 0.f ? v : 0.2f * v; p2 += v * av[j];
        }
#pragma unroll
        for (int j = 0; j < 8; ++j) {
            u3[j] = bf2f(q3[j]); float v = u3[j] + fdv[j]; v = v > 0.f ? v : 0.2f * v; p3 += v * av[j];
        }
        p0 += __shfl_xor(p0, 1); p0 += __shfl_xor(p0, 2);
        p1 += __shfl_xor(p1, 1); p1 += __shfl_xor(p1, 2);
        p2 += __shfl_xor(p2, 1); p2 += __shfl_xor(p2, 2);
        p3 += __shfl_xor(p3, 1); p3 += __shfl_xor(p3, 2);
        float mnew = fmaxf(fmaxf(fmaxf(p0, p1), fmaxf(p2, p3)), mx);
        float f  = __expf(mx - mnew);
        float w0 = __expf(p0 - mnew), w1 = __expf(p1 - mnew);
        float w2 = __expf(p2 - mnew), w3 = __expf(p3 - mnew);
        ssum = ssum * f + ((w0 + w1) + (w2 + w3));
#pragma unroll
        for (int j = 0; j < 8; ++j)
            acc[j] = acc[j] * f + w0 * u0[j] + w1 * u1[j] + w2 * u2[j] + w3 * u3[j];
        mx = mnew;
    }
    for (; i < e1; ++i) {
        int s0 = csrc[i];
        u16x8 q0 = *reinterpret_cast<const u16x8*>(fsP + (size_t)s0 * 128 + lane * 8);
        float u0[8];
        float p0 = 0.f;
#pragma unroll
        for (int j = 0; j < 8; ++j) {
            u0[j] = bf2f(q0[j]); float v = u0[j] + fdv[j]; v = v > 0.f ? v : 0.2f * v; p0 += v * av[j];
        }
        p0 += __shfl_xor(p0, 1); p0 += __shfl_xor(p0, 2);
        float mnew = fmaxf(mx, p0);
        float f = __expf(mx - mnew);
        float w = __expf(p0 - mnew);
        ssum = ssum * f + w;
#pragma unroll
        for (int j = 0; j < 8; ++j) acc[j] = acc[j] * f + w * u0[j];
        mx = mnew;
    }
    float inv = (ssum > 0.f) ? wscale / ssum : 0.f;
#pragma unroll
    for (int j = 0; j < 8; ++j) out[j] += inv * acc[j];
}

// ---------------------------------------------------------------------------
// Fused conv: relation A (+ optional relation B) into one dst row; bias folded;
// writes split bf16 hi|lo row [2*128] to sp.
// ---------------------------------------------------------------------------
__global__ __launch_bounds__(256) void gat_conv_fused_kernel(
    const unsigned short* __restrict__ fsA, const unsigned short* __restrict__ fdA,
    const int* __restrict__ offA, const int* __restrict__ csrA,
    const float* __restrict__ attnA, const float* __restrict__ biasA,
    const unsigned short* __restrict__ fsB, const unsigned short* __restrict__ fdB,
    const int* __restrict__ offB, const int* __restrict__ csrB,
    const float* __restrict__ attnB, const float* __restrict__ biasB,
    float wscale, unsigned short* __restrict__ sp, int n_dst)
{
    int gid = blockIdx.x * 256 + threadIdx.x;
    int d = gid >> 4, lane = gid & 15;
    if (d >= n_dst) return;
    float out[8];
#pragma unroll
    for (int j = 0; j < 8; ++j) {
        float b = biasA[lane * 8 + j];
        if (biasB) b += biasB[lane * 8 + j];
        out[j] = wscale * b;
    }
    rel_accum(fsA, fdA, offA, csrA, attnA, d, lane, wscale, out);
    if (fsB) rel_accum(fsB, fdB, offB, csrB, attnB, d, lane, wscale, out);
    u16x8 hv, lv;
#pragma unroll
    for (int j = 0; j < 8; ++j) {
        unsigned short h = f2bf(out[j]);
        hv[j] = h;
        lv[j] = f2bf(out[j] - bf2f(h));
    }
    *reinterpret_cast<u16x8*>(sp + (size_t)d * 256 + lane * 8) = hv;
    *reinterpret_cast<u16x8*>(sp + (size_t)d * 256 + 128 + lane * 8) = lv;
}

// ---------------------------------------------------------------------------
extern "C" void kernel_launch(void* const* d_in, const int* in_sizes, int n_in,
                              void* d_out, int out_size, void* d_ws, size_t ws_size,
                              hipStream_t stream)
{
    const float* x_word  = (const float*)d_in[0];
    const float* x_doc   = (const float*)d_in[1];
    const float* Wp_word = (const float*)d_in[2];
    const float* bp_word = (const float*)d_in[3];
    const float* Wp_doc  = (const float*)d_in[4];
    const float* bp_doc  = (const float*)d_in[5];
    const float* Wsrc    = (const float*)d_in[6];
    const float* bsrc    = (const float*)d_in[7];
    const float* Wdst    = (const float*)d_in[8];
    const float* bdst    = (const float*)d_in[9];
    const float* attn    = (const float*)d_in[10];
    const float* bconv   = (const float*)d_in[11];
    const float* Wc1     = (const float*)d_in[12];
    const float* bc1     = (const float*)d_in[13];
    const float* Wc2     = (const float*)d_in[14];
    const float* bc2     = (const float*)d_in[15];
    const int* src_wd = (const int*)d_in[16];
    const int* dst_wd = (const int*)d_in[17];
    const int* src_dw = (const int*)d_in[18];
    const int* dst_dw = (const int*)d_in[19];
    const int* src_dd = (const int*)d_in[20];
    const int* dst_dd = (const int*)d_in[21];

    // ---- workspace layout (all u16 then ints) ----
    const size_t NP = (size_t)NNODE * 128;   // one bf16 panel
    unsigned short* U = (unsigned short*)d_ws;
    unsigned short* Pfs_wd = U;              // panels (6)
    unsigned short* Pfd_dw = U + 1 * NP;
    unsigned short* Pfd_wd = U + 2 * NP;
    unsigned short* Pfs_dw = U + 3 * NP;
    unsigned short* Pfs_dd = U + 4 * NP;
    unsigned short* Pfd_dd = U + 5 * NP;
    unsigned short* AswA = U + 6 * NP;       // split h buffers [M][256]
    unsigned short* AsdA = AswA + 2 * NP;
    unsigned short* AswB = AsdA + 2 * NP;
    unsigned short* AsdB = AswB + 2 * NP;
    unsigned short* WtPw  = AsdB + 2 * NP;   // 2*128*320
    unsigned short* WtPd  = WtPw + 81920;    // 2*128*128
    unsigned short* WtCat = WtPd + 32768;    // 6 * 2*256*128
    unsigned short* WtC1  = WtCat + 393216;  // 2*64*128
    unsigned short* WtC2  = WtC1 + 16384;    // 2*64*64
    // overlays
    unsigned short* Ax  = Pfs_wd;            // x_word split [M][640] (dead before panels)
    unsigned short* Axd = AswB;              // x_doc split  [M][256] (dead before AswB use)
    unsigned short* Az  = AswB;              // MLP z split  [M][128] (after AswB consumed)
    int* I    = (int*)(WtC2 + 8192);
    int* cnt  = I;                           // 3*NNODE
    int* off0 = I + 3 * NNODE;
    int* off1 = off0 + 20004;
    int* off2 = off1 + 20004;
    int* csr  = off2 + 20004;                // 3*NEDGE contiguous

    const int GB = (NNODE + 63) / 64;              // 313
    const int CB = (NNODE * 16 + 255) / 256;       // 1250
    const int E3 = (3 * NEDGE + 255) / 256;

    // ---- CSR build ----
    (void)hipMemsetAsync(cnt, 0, 3 * NNODE * sizeof(int), stream);
    count3_kernel<<<E3, 256, 0, stream>>>(dst_wd, dst_dw, dst_dd, cnt, NEDGE);
    scan3_kernel<<<3, 1024, 0, stream>>>(cnt, off0, cnt + NNODE, off1,
                                         cnt + 2 * NNODE, off2, NNODE);
    (void)hipMemsetAsync(cnt, 0, 3 * NNODE * sizeof(int), stream);
    fill3_kernel<<<E3, 256, 0, stream>>>(src_wd, dst_wd, src_dw, dst_dw,
                                         src_dd, dst_dd, off0, off1, off2,
                                         cnt, csr, NEDGE);

    // ---- weight splits ----
    split_b_kernel<<<(128 * 320 + 255) / 256, 256, 0, stream>>>(Wp_word, WtPw, 300, 128, 320);
    split_b_kernel<<<(128 * 128 + 255) / 256, 256, 0, stream>>>(Wp_doc, WtPd, 128, 128, 128);
    split_cat_kernel<<<(6 * 256 * 128 + 255) / 256, 256, 0, stream>>>(Wsrc, Wdst, WtCat);
    split_b_kernel<<<(64 * 128 + 255) / 256, 256, 0, stream>>>(Wc1, WtC1, 128, 64, 128);
    split_b_kernel<<<(64 * 64 + 255) / 256, 256, 0, stream>>>(Wc2, WtC2, 64, 64, 64);

    // ---- x splits + projections (emit split h) ----
    split_a_kernel<<<(NNODE * 80 + 255) / 256, 256, 0, stream>>>(x_word, Ax, NNODE, 300, 320);
    split_a_kernel<<<(NNODE * 32 + 255) / 256, 256, 0, stream>>>(x_doc, Axd, NNODE, 128, 128);
    gemm_mfma_kernel<128, 2><<<GB, 256, 0, stream>>>(
        Ax, WtPw, bp_word, nullptr, AswA, NNODE, 320, 0);
    gemm_mfma_kernel<128, 2><<<GB, 256, 0, stream>>>(
        Axd, WtPd, bp_doc, nullptr, AsdA, NNODE, 128, 0);

    // ---- 2 GAT layers ----
    const unsigned short* Asw_in = AswA;
    const unsigned short* Asd_in = AsdA;
    for (int l = 0; l < 2; ++l) {
        const int l3 = l * 3;
        Cat3Args ca;
        ca.A[0] = Asw_in; ca.A[1] = Asd_in; ca.A[2] = Asd_in;
        ca.Bt[0] = WtCat + (size_t)(l3 + 0) * 65536;
        ca.Bt[1] = WtCat + (size_t)(l3 + 1) * 65536;
        ca.Bt[2] = WtCat + (size_t)(l3 + 2) * 65536;
        ca.bs0[0] = bsrc + (l3 + 0) * 128; ca.bs1[0] = bdst + (l3 + 1) * 128;
        ca.bs0[1] = bdst + (l3 + 0) * 128; ca.bs1[1] = bsrc + (l3 + 1) * 128;
        ca.bs0[2] = bsrc + (l3 + 2) * 128; ca.bs1[2] = bdst + (l3 + 2) * 128;
        ca.P0[0] = Pfs_wd; ca.P1[0] = Pfd_dw;
        ca.P0[1] = Pfd_wd; ca.P1[1] = Pfs_dw;
        ca.P0[2] = Pfs_dd; ca.P1[2] = Pfd_dd;
        gemm_cat3_kernel<<<dim3(GB, 3), 256, 0, stream>>>(ca, NNODE);

        // doc conv: rel0 + rel2, writes split h_d
        gat_conv_fused_kernel<<<CB, 256, 0, stream>>>(
            Pfs_wd, Pfd_wd, off0, csr,             attn + (l3 + 0) * 128, bconv + (l3 + 0) * 128,
            Pfs_dd, Pfd_dd, off2, csr + 2 * NEDGE, attn + (l3 + 2) * 128, bconv + (l3 + 2) * 128,
            0.5f, (l == 0 ? AsdB : AsdA), NNODE);
        // word conv: rel1 only — dead in layer 2 (output unused)
        if (l == 0) {
            gat_conv_fused_kernel<<<CB, 256, 0, stream>>>(
                Pfs_dw, Pfd_dw, off1, csr + NEDGE, attn + (l3 + 1) * 128, bconv + (l3 + 1) * 128,
                nullptr, nullptr, nullptr, nullptr, nullptr, nullptr,
                1.0f, AswB, NNODE);
        }
        Asw_in = AswB;
        Asd_in = AsdB;
    }

    // ---- final MLP: z = relu(hd @ Wc1 + bc1) (split); out = z @ Wc2 + bc2 ----
    gemm_mfma_kernel<64, 2><<<GB, 256, 0, stream>>>(
        AsdA, WtC1, bc1, nullptr, Az, NNODE, 128, 1);
    gemm_mfma_kernel<64, 0><<<GB, 256, 0, stream>>>(
        Az, WtC2, bc2, (float*)d_out, nullptr, NNODE, 64, 0);
}